// Round 7
// baseline (397.305 us; speedup 1.0000x reference)
//
#include <hip/hip_runtime.h>
#include <math.h>

#define HH 1536
#define WW 1536
#define HWSZ (HH*WW)
#define NT 256        // 4 waves/block, 2 px/thread -> 512 px = 1/3 row
#define NBLK (HH*3)   // 4608 blocks
#define BAND (NBLK/8) // 576 blocks per XCD band

// Session lessons (rounds 1-6):
//  - Wave tiers at VGPR={64,128,256}. R0/R5/R6 (112/72/88 VGPR) all ~115us:
//    everything inside the 4-waves/SIMD tier is equivalent. Must reach <=64.
//  - Unconstrained allocator won't pick 64 (R6: chose 88, spent slack on load
//    pipelining). __launch_bounds__(256, k) DOES force the 64-VGPR target (R1).
//    R1 spilled only because 80-float state couldn't fit; now ~26 floats.
//  - __shfl x-halos (R3) and per-block __threadfence finalize (R4) regress.
//    Keep redundant halo loads + separate finalize dispatch.
//  - This round: (a) force 8 blocks/CU, (b) fold means+sensory into q[] so
//    Pass B persistent state is just q[10][2] + offsets, (c) native
//    transcendentals to cut live temps (absmax unchanged R1-R4).

__device__ __forceinline__ float2 LD2(const float* __restrict__ p, int row, int idx) {
    return reinterpret_cast<const float2*>(p + row)[idx];
}

__global__ __launch_bounds__(NT, 8) void step_kernel(
    const float* __restrict__ phi,
    const float* __restrict__ sensory,
    const float* __restrict__ gamma,
    const float* __restrict__ alpha,
    const float* __restrict__ mixw,
    float* __restrict__ out,
    float* __restrict__ sums)
{
    __shared__ float s_mix[100];
    __shared__ float s_red[4][10];

    const int tid = threadIdx.x;
    if (tid < 100) s_mix[tid] = mixw[tid];
    __syncthreads();

    // XCD-banded swizzle: 4608 blocks round-robin over 8 XCDs; each XCD gets a
    // contiguous 576-block band = 192 rows, so stencil row-reuse hits its own L2.
    const int blk  = blockIdx.x;
    const int nb   = (blk & 7) * BAND + (blk >> 3);
    const int y    = nb / 3;            // row
    const int part = nb - y * 3;        // third of the row

    const int col = part * NT + tid;    // float2 index within row
    const int x0  = col * 2;            // first pixel x of this thread

    const int ym1 = (y == 0)      ? HH - 1     : y - 1;
    const int yp1 = (y == HH - 1) ? 0          : y + 1;
    const int ym2 = (y < 2)       ? y + HH - 2 : y - 2;
    const int yp2 = (y >= HH - 2) ? y - HH + 2 : y + 2;

    const int r0  = y   * WW;   // block-uniform -> SGPRs
    const int rm1 = ym1 * WW;
    const int rp1 = yp1 * WW;
    const int rm2 = ym2 * WW;
    const int rp2 = yp2 * WW;

    // x halo indices (x0 multiple of 2; x0==0 is the only left-wrap case)
    const int xl1 = (x0 == 0)      ? WW - 1 : x0 - 1;
    const int xl2 = (x0 == 0)      ? WW - 2 : x0 - 2;
    const int xr1 = (x0 + 2 == WW) ? 0      : x0 + 2;
    const int xr2 = (x0 + 2 == WW) ? 1      : x0 + 3;

    // gamma/alpha: uniform indices on const restrict ptr -> scalar loads (SGPRs)
    const float g0 = gamma[0], g1 = gamma[1], g2 = gamma[2], g3 = gamma[3], g4 = gamma[4];
    const float g5 = gamma[5], g6 = gamma[6], g7 = gamma[7], g8 = gamma[8], g9 = gamma[9];
    const float a0 = alpha[0];

    // ---- Pass A: center values -> fused coupling/mean/sensory term q[] ----
    // q[c] = EPS*coupling[c] + (S2F*slow_mean | F2S*fast_mean) + sensory terms,
    // i.e. everything in dphi[c] except the stencil+nonlinear part.
    float q[10][2];
    #pragma unroll
    for (int o = 0; o < 10; ++o) { q[o][0] = 0.0f; q[o][1] = 0.0f; }
    float fm0 = 0.f, fm1 = 0.f, sm0 = 0.f, sm1 = 0.f;

    #pragma unroll
    for (int c = 0; c < 10; ++c) {
        const float2 v = LD2(phi + (size_t)c * HWSZ, r0, col);
        #pragma unroll
        for (int o = 0; o < 10; ++o) {
            const float m = s_mix[o * 10 + c];   // wave-uniform -> LDS broadcast
            q[o][0] = fmaf(m, v.x, q[o][0]);
            q[o][1] = fmaf(m, v.y, q[o][1]);
        }
        if (c < 5) { fm0 += v.x; fm1 += v.y; }
        else       { sm0 += v.x; sm1 += v.y; }
    }
    fm0 *= 0.2f; fm1 *= 0.2f; sm0 *= 0.2f; sm1 *= 0.2f;

    {
        const float2 sd2 = LD2(sensory, r0, col);
        // fast channels: 0.06*cp + 0.02*slow_mean ; slow: 0.02*cp + 0.04*fast_mean
        #pragma unroll
        for (int o = 0; o < 5; ++o) {
            q[o][0] = 0.06f * q[o][0] + 0.02f * sm0;
            q[o][1] = 0.06f * q[o][1] + 0.02f * sm1;
        }
        #pragma unroll
        for (int o = 5; o < 10; ++o) {
            q[o][0] = 0.02f * q[o][0] + 0.04f * fm0;
            q[o][1] = 0.02f * q[o][1] + 0.04f * fm1;
        }
        q[0][0] += 0.2f  * sd2.x;        q[0][1] += 0.2f  * sd2.y;
        q[4][0] += 0.08f * fabsf(sd2.x); q[4][1] += 0.08f * fabsf(sd2.y);
        q[9][0] += 0.05f * sd2.x;        q[9][1] += 0.05f * sd2.y;
    }
    // fm/sm/sd now dead: persistent state across Pass B = q[10][2] + offsets.

    const int lane = tid & 63;
    const int wave = tid >> 6;

    // ---- Pass B: per-channel stencil + nonlinear + integrate + store ----
    #pragma unroll
    for (int c = 0; c < 10; ++c) {
        const float* pc = phi + (size_t)c * HWSZ;
        const float2 cm = LD2(pc, r0,  col);     // center reload: L1/L2 hit
        const float2 nn = LD2(pc, rm1, col);
        const float2 ss = LD2(pc, rp1, col);
        const float wl1 = pc[r0 + xl1];
        const float wr1 = pc[r0 + xr1];

        float lap[2];
        lap[0] = nn.x + ss.x + wl1  + cm.y - 4.0f * cm.x;
        lap[1] = nn.y + ss.y + cm.x + wr1  - 4.0f * cm.y;

        float bl[2] = {0.f, 0.f};
        if (c == 0 || c == 3 || c == 4 || c == 9) {
            // direct 13-pt bilaplacian: 20c -8(N+S+W+E) +2(diag) + (NN+SS+WW+EE)
            const float2 t2n = LD2(pc, rm2, col);
            const float2 t2s = LD2(pc, rp2, col);
            const float wl2 = pc[r0  + xl2];
            const float wr2 = pc[r0  + xr2];
            const float nwl = pc[rm1 + xl1];
            const float ner = pc[rm1 + xr1];
            const float swl = pc[rp1 + xl1];
            const float ser = pc[rp1 + xr1];
            bl[0] = 20.0f*cm.x - 8.0f*(nn.x + ss.x + wl1  + cm.y)
                  + 2.0f*(nwl  + nn.y + swl + ss.y) + (t2n.x + t2s.x + wl2 + wr1);
            bl[1] = 20.0f*cm.y - 8.0f*(nn.y + ss.y + cm.x + wr1)
                  + 2.0f*(nn.x + ner  + ss.x + ser) + (t2n.y + t2s.y + wl1 + wr2);
        }

        const float pvk[2] = {cm.x, cm.y};
        float pn[2];
        #pragma unroll
        for (int k = 0; k < 2; ++k) {
            const float pp = pvk[k];
            const float lv = lap[k];
            const float bv = bl[k];
            float dd;
            switch (c) {
            case 0: dd = -g0*lv - a0*pp*pp*pp + 0.12f*bv; break;
            case 1: dd = -g1*lv + 0.15f*__sinf(pp) + 0.08f*pp*pp*pp; break;
            case 2: dd = -g2*lv + 0.2f*pp*(1.0f - pp*pp); break;
            case 3: { const float p2 = pp*pp;
                      dd = -g3*lv - 0.03f*p2*p2*pp + 0.08f*bv; } break;
            case 4: dd = -g4*lv + 0.12f*pp*__logf(fabsf(pp) + 1e-6f) + 0.02f*bv; break;
            case 5: { const float p2 = pp*pp;
                      dd = -g5*lv + 0.08f*p2*pp - 0.02f*p2*p2*pp; } break;
            case 6: { const float p2 = pp*pp;
                      dd = -g6*lv + 0.06f*p2*p2 - 0.04f*pp; } break;
            case 7: { const float pc7 = fminf(fmaxf(pp, -2.0f), 2.0f);
                      const float ex  = __expf(pc7);
                      const float exm = __expf(-pc7);
                      dd = -g7*lv + 0.04f*(ex - exm); } break;   // 0.08*sinh
            case 8: dd = -g8*lv + 0.05f*pp*pp - 0.08f*pp; break;
            default: { const float p3 = pp*pp*pp;
                       dd = -g9*lv + 0.02f*p3*p3 - 0.04f*p3 + 0.01f*bv; } break;
            }

            dd += q[c][k];                       // coupling + means + sensory, prefused
            const float dtc = (c < 5) ? 0.02f : 0.004f;   // DT*FAST_DT / DT*SLOW_DT
            pn[k] = fminf(fmaxf(fmaf(dtc, dd, pp), -4.0f), 4.0f);
        }

        float2 o2; o2.x = pn[0]; o2.y = pn[1];
        reinterpret_cast<float2*>(out + (size_t)c * HWSZ + r0)[col] = o2;

        float s = pn[0] + pn[1];
        #pragma unroll
        for (int off = 32; off > 0; off >>= 1) s += __shfl_down(s, off, 64);
        if (lane == 0) s_red[wave][c] = s;
    }

    __syncthreads();
    if (tid < 10) {
        float v = 0.0f;
        #pragma unroll
        for (int w = 0; w < 4; ++w) v += s_red[w][tid];
        atomicAdd(&sums[tid], v);
    }
}

__global__ void finalize_kernel(const float* __restrict__ sums,
                                float* __restrict__ out)
{
    const int t = threadIdx.x;
    const float inv = 1.0f / (float)HWSZ;
    const size_t base = (size_t)10 * HWSZ;
    if (t == 0) out[base]     = sums[0] * inv;  // phi1_mean (channel 0)
    if (t == 1) out[base + 1] = sums[4] * inv;  // phi5_mean (channel 4)
    if (t >= 2 && t < 12) out[base + 2 + (t - 2)] = sums[t - 2] * inv;  // field_means
}

extern "C" void kernel_launch(void* const* d_in, const int* in_sizes, int n_in,
                              void* d_out, int out_size, void* d_ws, size_t ws_size,
                              hipStream_t stream) {
    const float* phi     = (const float*)d_in[0];
    const float* sensory = (const float*)d_in[1];
    const float* gamma   = (const float*)d_in[2];
    const float* alpha   = (const float*)d_in[3];
    const float* mixw    = (const float*)d_in[4];
    float* out = (float*)d_out;
    float* sums = (float*)d_ws;

    hipMemsetAsync(sums, 0, 10 * sizeof(float), stream);

    step_kernel<<<dim3(NBLK), NT, 0, stream>>>(phi, sensory, gamma, alpha, mixw, out, sums);
    finalize_kernel<<<1, 64, 0, stream>>>(sums, out);
}